// Round 1
// baseline (10140.597 us; speedup 1.0000x reference)
//
#include <hip/hip_runtime.h>
#include <math.h>

#define N_PTS 16384
#define N_CLUSTERS 4096
#define KNN_K 16
#define C_IN 64
#define C_OUT 128
#define FAN_IN 67
#define N_ROWS (N_CLUSTERS * KNN_K)   // 65536

// ---------------------------------------------------------------------------
// init: pp[i] = |pos_i|^2 (reference op order, no FMA), zero colsum/colsumsq
// ---------------------------------------------------------------------------
__global__ void init_kernel(const float* __restrict__ pos, float* __restrict__ pp,
                            float* __restrict__ cz) {
#pragma clang fp contract(off)
    int i = blockIdx.x * 256 + threadIdx.x;
    if (i < N_PTS) {
        float a = pos[i * 3 + 0], b = pos[i * 3 + 1], c = pos[i * 3 + 2];
        pp[i] = ((a * a) + (b * b)) + (c * c);
    }
    if (blockIdx.x == 0 && threadIdx.x < 256) cz[threadIdx.x] = 0.0f;
}

// ---------------------------------------------------------------------------
// FPS: single block, 1024 threads, 16 points/thread in registers.
// Bit-exact replication of reference: d = ((dx*dx)+(dy*dy))+(dz*dz), no FMA,
// argmax with first-index tie-break.
// ---------------------------------------------------------------------------
__global__ __launch_bounds__(1024) void fps_kernel(const float* __restrict__ pos,
                                                   int* __restrict__ clusters) {
#pragma clang fp contract(off)
    __shared__ float s_rv[16];
    __shared__ int   s_ri[16];
    __shared__ float s_last[3];
    const int t = threadIdx.x;

    float px[16], py[16], pz[16], md[16];
#pragma unroll
    for (int j = 0; j < 16; ++j) {
        int idx = t + (j << 10);
        px[j] = pos[idx * 3 + 0];
        py[j] = pos[idx * 3 + 1];
        pz[j] = pos[idx * 3 + 2];
        md[j] = __builtin_inff();
    }
    if (t == 0) {
        clusters[0] = 0;
        s_last[0] = px[0]; s_last[1] = py[0]; s_last[2] = pz[0];
    }
    __syncthreads();

    const int lane = t & 63;
    for (int step = 1; step < N_CLUSTERS; ++step) {
        const float lx = s_last[0], ly = s_last[1], lz = s_last[2];
        float bv = -__builtin_inff();
        int   bj = 0;
#pragma unroll
        for (int j = 0; j < 16; ++j) {
            float dx = px[j] - lx, dy = py[j] - ly, dz = pz[j] - lz;
            float d = ((dx * dx) + (dy * dy)) + (dz * dz);
            float m = fminf(md[j], d);
            md[j] = m;
            // within a thread, j ascending => idx ascending: strict > keeps first
            bool better = (m > bv);
            bv = better ? m : bv;
            bj = better ? j : bj;
        }
        int bi = t + (bj << 10);
        // wave (64) reduce: max value, tie -> lower index
#pragma unroll
        for (int off = 32; off >= 1; off >>= 1) {
            float ov = __shfl_down(bv, off);
            int   oi = __shfl_down(bi, off);
            bool better = (ov > bv) || (ov == bv && oi < bi);
            bv = better ? ov : bv;
            bi = better ? oi : bi;
        }
        if (lane == 0) { s_rv[t >> 6] = bv; s_ri[t >> 6] = bi; }
        __syncthreads();
        // every wave redundantly reduces the 16 partials -> all know winner
        float rv = (lane < 16) ? s_rv[lane] : -__builtin_inff();
        int   ri = (lane < 16) ? s_ri[lane] : 0x7fffffff;
#pragma unroll
        for (int off = 8; off >= 1; off >>= 1) {
            float ov = __shfl_down(rv, off);
            int   oi = __shfl_down(ri, off);
            bool better = (ov > rv) || (ov == rv && oi < ri);
            rv = better ? ov : rv;
            ri = better ? oi : ri;
        }
        int win = __shfl(ri, 0);
        if (t == (win & 1023)) {
            int jw = win >> 10;
#pragma unroll
            for (int j = 0; j < 16; ++j) {
                if (j == jw) { s_last[0] = px[j]; s_last[1] = py[j]; s_last[2] = pz[j]; }
            }
            clusters[step] = win;
        }
        __syncthreads();
    }
}

// ---------------------------------------------------------------------------
// kNN: one block per cluster, 256 threads. d = (qq+pp) - 2*dot (dot FMA-
// ascending like BLAS), LDS distance array per 8192-chunk, 16 argmin rounds
// per chunk (tie -> lower index == stable top_k), exact merge of 2x16.
// Only the neighbor SET matters downstream.
// ---------------------------------------------------------------------------
__global__ __launch_bounds__(256) void knn_kernel(const float* __restrict__ pos,
                                                  const float* __restrict__ pp,
                                                  const int* __restrict__ clusters,
                                                  int* __restrict__ nbr) {
#pragma clang fp contract(off)
    __shared__ float s_d[8192];
    __shared__ float s_rv[4];
    __shared__ int   s_ri[4];
    __shared__ float s_tv[32];
    __shared__ int   s_ti[32];
    const int m = blockIdx.x, t = threadIdx.x;
    const int lane = t & 63, w = t >> 6;

    const int qi = clusters[m];
    const float qx = pos[qi * 3 + 0], qy = pos[qi * 3 + 1], qz = pos[qi * 3 + 2];
    const float qq = ((qx * qx) + (qy * qy)) + (qz * qz);

    for (int chunk = 0; chunk < 2; ++chunk) {
        const int base = chunk << 13;
        __syncthreads();  // protect s_d overwrite vs previous chunk's reads
        for (int i = t; i < 8192; i += 256) {
            const int p = base + i;
            float dot = fmaf(qx, pos[p * 3 + 0], 0.0f);
            dot = fmaf(qy, pos[p * 3 + 1], dot);
            dot = fmaf(qz, pos[p * 3 + 2], dot);
            s_d[i] = (qq + pp[p]) - 2.0f * dot;
        }
        __syncthreads();
        for (int r = 0; r < KNN_K; ++r) {
            float bv = __builtin_inff();
            int   bi = 0x7fffffff;
            for (int i = t; i < 8192; i += 256) {   // i ascending per thread
                float v = s_d[i];
                if (v < bv) { bv = v; bi = i; }     // strict < keeps first
            }
#pragma unroll
            for (int off = 32; off >= 1; off >>= 1) {
                float ov = __shfl_down(bv, off);
                int   oi = __shfl_down(bi, off);
                if (ov < bv || (ov == bv && oi < bi)) { bv = ov; bi = oi; }
            }
            if (lane == 0) { s_rv[w] = bv; s_ri[w] = bi; }
            __syncthreads();
            if (t == 0) {
                float fv = s_rv[0]; int fi = s_ri[0];
#pragma unroll
                for (int ww = 1; ww < 4; ++ww) {
                    if (s_rv[ww] < fv || (s_rv[ww] == fv && s_ri[ww] < fi)) {
                        fv = s_rv[ww]; fi = s_ri[ww];
                    }
                }
                s_tv[chunk * 16 + r] = fv;
                s_ti[chunk * 16 + r] = base + fi;
                s_d[fi] = __builtin_inff();
            }
            __syncthreads();
        }
    }
    if (t == 0) {   // exact merge of two sorted-by-(v,idx) lists
        int a = 0, b = 0;
        for (int r = 0; r < KNN_K; ++r) {
            bool takeA;
            if (b >= 16) takeA = true;
            else if (a >= 16) takeA = false;
            else {
                float va = s_tv[a], vb = s_tv[16 + b];
                takeA = (va < vb) || (va == vb && s_ti[a] < s_ti[16 + b]);
            }
            nbr[m * KNN_K + r] = takeA ? s_ti[a] : s_ti[16 + b];
            if (takeA) ++a; else ++b;
        }
    }
}

// ---------------------------------------------------------------------------
// MLP: grouped[r] = [pos[n]-pos[r>>4] (quirky full-pos indexing!), x[n]],
// h = grouped @ W^T.  PASS 1: accumulate column sum/sumsq.  PASS 2:
// recompute, y = scale*h+shift, out[m,c] = relu(max_k y) (relu∘max=max∘relu),
// plus sub_pos / sub_batch.  64 rows (= 4 whole clusters) x 128 cols / block.
// ---------------------------------------------------------------------------
template <int PASS>
__global__ __launch_bounds__(256) void mlp_kernel(const float* __restrict__ x,
                                                  const float* __restrict__ pos,
                                                  const int* __restrict__ nbr,
                                                  const float* __restrict__ W,
                                                  float* __restrict__ colsum,
                                                  float* __restrict__ colsumsq,
                                                  const float* __restrict__ ss,
                                                  const int* __restrict__ clusters,
                                                  const int* __restrict__ batch,
                                                  float* __restrict__ out) {
    __shared__ __align__(16) float At[FAN_IN][68];     // [i][r], pad 68
    __shared__ __align__(16) float Wl[FAN_IN * 132];   // [i][c], pad 132
    __shared__ float red0[128], red1[128];
    __shared__ float hm[8][132];                       // pass2 half-cluster maxima
    const int tid = threadIdx.x;
    const int R0 = blockIdx.x * 64;

    // stage W transposed
    for (int idx = tid; idx < FAN_IN * 128; idx += 256) {
        int i = idx >> 7, c = idx & 127;
        Wl[i * 132 + c] = W[c * FAN_IN + i];
    }
    // stage A transposed (gather)
    {
        const int wv = tid >> 6, lane = tid & 63;
        for (int r = wv; r < 64; r += 4) {
            const int R = R0 + r;
            const int n = nbr[R];
            At[3 + lane][r] = x[n * C_IN + lane];
            if (lane < 3) {
                const int q = R >> 4;  // faithful to source: cluster ORDINAL indexes pos
                At[lane][r] = pos[n * 3 + lane] - pos[q * 3 + lane];
            }
        }
    }
    if (PASS == 1 && tid < 128) { red0[tid] = 0.0f; red1[tid] = 0.0f; }
    __syncthreads();

    const int g = tid & 31, rg = tid >> 5;
    const int c0 = g * 4, r0 = rg * 8;
    float acc[8][4];
#pragma unroll
    for (int a = 0; a < 8; ++a)
#pragma unroll
        for (int b = 0; b < 4; ++b) acc[a][b] = 0.0f;

    for (int i = 0; i < FAN_IN; ++i) {
        const float4 w4 = *(const float4*)&Wl[i * 132 + c0];
        const float4 a0 = *(const float4*)&At[i][r0];
        const float4 a1 = *(const float4*)&At[i][r0 + 4];
        const float av[8] = {a0.x, a0.y, a0.z, a0.w, a1.x, a1.y, a1.z, a1.w};
        const float wv4[4] = {w4.x, w4.y, w4.z, w4.w};
#pragma unroll
        for (int a = 0; a < 8; ++a)
#pragma unroll
            for (int b = 0; b < 4; ++b) acc[a][b] = fmaf(av[a], wv4[b], acc[a][b]);
    }

    if (PASS == 1) {
#pragma unroll
        for (int b = 0; b < 4; ++b) {
            float s = 0.0f, sq = 0.0f;
#pragma unroll
            for (int a = 0; a < 8; ++a) {
                s += acc[a][b];
                sq = fmaf(acc[a][b], acc[a][b], sq);
            }
            atomicAdd(&red0[c0 + b], s);
            atomicAdd(&red1[c0 + b], sq);
        }
        __syncthreads();
        if (tid < 128) {
            atomicAdd(&colsum[tid], red0[tid]);
            atomicAdd(&colsumsq[tid], red1[tid]);
        }
    } else {
        // rows r0..r0+7 lie in ONE cluster (half of it): reduce then combine
#pragma unroll
        for (int b = 0; b < 4; ++b) {
            const float sc = ss[c0 + b], sh = ss[128 + c0 + b];
            float mx = -__builtin_inff();
#pragma unroll
            for (int a = 0; a < 8; ++a) mx = fmaxf(mx, fmaf(sc, acc[a][b], sh));
            hm[rg][c0 + b] = mx;
        }
        __syncthreads();
        for (int o = tid; o < 512; o += 256) {
            const int cl = o >> 7, c = o & 127;
            const float v = fmaxf(hm[2 * cl][c], hm[2 * cl + 1][c]);
            const int M = blockIdx.x * 4 + cl;
            out[M * 128 + c] = fmaxf(v, 0.0f);
        }
        if (tid < 12) {
            const int cl = tid / 3, l = tid % 3;
            const int M = blockIdx.x * 4 + cl;
            out[524288 + M * 3 + l] = pos[clusters[M] * 3 + l];
        } else if (tid < 16) {
            const int M = blockIdx.x * 4 + (tid - 12);
            out[536576 + M] = (float)batch[clusters[M]];
        }
    }
}

// ---------------------------------------------------------------------------
// stats: scale/shift from column sums (biased var, like torch BN training)
// ---------------------------------------------------------------------------
__global__ void stats_kernel(const float* __restrict__ colsum,
                             const float* __restrict__ colsumsq,
                             const float* __restrict__ gamma,
                             const float* __restrict__ beta,
                             float* __restrict__ ss) {
    const int c = threadIdx.x;
    const float inv_n = 1.0f / (float)N_ROWS;
    const float mean = colsum[c] * inv_n;
    float var = colsumsq[c] * inv_n - mean * mean;
    var = fmaxf(var, 0.0f);
    const float inv = rsqrtf(var + 1e-5f);
    const float sc = gamma[c] * inv;
    ss[c] = sc;
    ss[128 + c] = beta[c] - mean * sc;
}

// ---------------------------------------------------------------------------
extern "C" void kernel_launch(void* const* d_in, const int* in_sizes, int n_in,
                              void* d_out, int out_size, void* d_ws, size_t ws_size,
                              hipStream_t stream) {
    const float* x     = (const float*)d_in[0];
    const float* pos   = (const float*)d_in[1];
    const int*   batch = (const int*)d_in[2];
    const float* W     = (const float*)d_in[3];
    const float* gamma = (const float*)d_in[4];
    const float* beta  = (const float*)d_in[5];
    float* out = (float*)d_out;
    float* wsf = (float*)d_ws;

    int*   clusters = (int*)d_ws;            // [4096]
    int*   nbr      = clusters + 4096;       // [65536]
    float* pp       = wsf + 69632;           // [16384]
    float* colsum   = wsf + 86016;           // [128]
    float* colsumsq = wsf + 86144;           // [128]
    float* ss       = wsf + 86272;           // [256]

    init_kernel<<<dim3(64), dim3(256), 0, stream>>>(pos, pp, colsum);
    fps_kernel<<<dim3(1), dim3(1024), 0, stream>>>(pos, clusters);
    knn_kernel<<<dim3(N_CLUSTERS), dim3(256), 0, stream>>>(pos, pp, clusters, nbr);
    mlp_kernel<1><<<dim3(1024), dim3(256), 0, stream>>>(x, pos, nbr, W, colsum, colsumsq,
                                                        ss, clusters, batch, out);
    stats_kernel<<<dim3(1), dim3(128), 0, stream>>>(colsum, colsumsq, gamma, beta, ss);
    mlp_kernel<2><<<dim3(1024), dim3(256), 0, stream>>>(x, pos, nbr, W, colsum, colsumsq,
                                                        ss, clusters, batch, out);
}

// Round 2
// 7674.986 us; speedup vs baseline: 1.3213x; 1.3213x over previous
//
#include <hip/hip_runtime.h>
#include <math.h>

#define N_PTS 16384
#define N_CLUSTERS 4096
#define KNN_K 16
#define C_IN 64
#define C_OUT 128
#define FAN_IN 67
#define N_ROWS (N_CLUSTERS * KNN_K)   // 65536

// ---------------------------------------------------------------------------
// init: pp[i] = |pos_i|^2 (reference op order, no FMA), zero colsum/colsumsq
// ---------------------------------------------------------------------------
__global__ void init_kernel(const float* __restrict__ pos, float* __restrict__ pp,
                            float* __restrict__ cz) {
#pragma clang fp contract(off)
    int i = blockIdx.x * 256 + threadIdx.x;
    if (i < N_PTS) {
        float a = pos[i * 3 + 0], b = pos[i * 3 + 1], c = pos[i * 3 + 2];
        pp[i] = ((a * a) + (b * b)) + (c * c);
    }
    if (blockIdx.x == 0 && threadIdx.x < 256) cz[threadIdx.x] = 0.0f;
}

// ---------------------------------------------------------------------------
// FPS v2: single block, 1024 threads, 16 points/thread in registers.
// Bit-exact replication of reference: d = ((dx*dx)+(dy*dy))+(dz*dz), no FMA,
// argmax with first-index tie-break.
//   - value-only inner loop (10 VALU inst/pt), post-scan recovers index
//   - wave64 reduce via DPP (VALU pipes, no ds_bpermute serialization)
//   - ONE __syncthreads per step: per-wave LDS atomicMax on packed u64 key
//     (dist_bits<<32 | ~idx) into 4-slot rotating buffer (race-free reset),
//     winner coords re-fetched via scalar loads (no 2nd barrier)
// ---------------------------------------------------------------------------
__global__ __launch_bounds__(1024, 4) void fps_kernel(const float* __restrict__ pos,
                                                      int* __restrict__ clusters) {
#pragma clang fp contract(off)
    __shared__ unsigned long long s_key[4];
    const int t = threadIdx.x;

    float px[16], py[16], pz[16], md[16];
#pragma unroll
    for (int j = 0; j < 16; ++j) {
        int idx = t + (j << 10);
        px[j] = pos[idx * 3 + 0];
        py[j] = pos[idx * 3 + 1];
        pz[j] = pos[idx * 3 + 2];
        md[j] = __builtin_inff();
    }
    if (t == 0) clusters[0] = 0;
    if (t < 4) s_key[t] = 0ULL;
    // first selected point is index 0; all waves read its coords uniformly
    float lx = pos[0], ly = pos[1], lz = pos[2];
    __syncthreads();

// DPP pair-max stage: (hi,lo) = max over incoming lanes, key order = u64.
// old=0 for masked/invalid lanes: key 0 never wins (hi = dist bits > 0).
#define PAIR_STAGE(CTRL, RM)                                                          \
    do {                                                                              \
        unsigned int ohi = (unsigned int)__builtin_amdgcn_update_dpp(                 \
            0, (int)hi, (CTRL), (RM), 0xF, false);                                    \
        unsigned int olo = (unsigned int)__builtin_amdgcn_update_dpp(                 \
            0, (int)lo, (CTRL), (RM), 0xF, false);                                    \
        unsigned long long cur = ((unsigned long long)hi << 32) | lo;                 \
        unsigned long long oth = ((unsigned long long)ohi << 32) | olo;               \
        if (oth > cur) { hi = ohi; lo = olo; }                                        \
    } while (0)

    for (int step = 1; step < N_CLUSTERS; ++step) {
        // --- update min distances, track max value only (10 inst/pt) ---
        float bv = 0.0f;
#pragma unroll
        for (int j = 0; j < 16; ++j) {
            float dx = px[j] - lx, dy = py[j] - ly, dz = pz[j] - lz;
            float d = ((dx * dx) + (dy * dy)) + (dz * dz);
            float m = fminf(md[j], d);
            md[j] = m;
            bv = fmaxf(bv, m);
        }
        // --- recover first (smallest) local index achieving bv ---
        int bj = 0;
#pragma unroll
        for (int j = 15; j >= 0; --j) bj = (md[j] == bv) ? j : bj;
        const unsigned int bi = (unsigned int)(t + (bj << 10));

        // --- wave64 DPP pair-max; result lands in lane 63 ---
        unsigned int hi = __float_as_uint(bv);
        unsigned int lo = ~bi;  // max(~idx) == min(idx) tie-break
        PAIR_STAGE(0x111, 0xF);  // row_shr:1
        PAIR_STAGE(0x112, 0xF);  // row_shr:2
        PAIR_STAGE(0x114, 0xF);  // row_shr:4
        PAIR_STAGE(0x118, 0xF);  // row_shr:8
        PAIR_STAGE(0x142, 0xA);  // row_bcast:15 -> rows 1,3
        PAIR_STAGE(0x143, 0xC);  // row_bcast:31 -> rows 2,3

        if ((t & 63) == 63)
            atomicMax(&s_key[step & 3], (((unsigned long long)hi << 32) | lo));
        if (t == 0) s_key[(step + 2) & 3] = 0ULL;  // reset slot for step+2
        __syncthreads();

        const unsigned long long k = s_key[step & 3];
        const unsigned int win = ~((unsigned int)k);
        if (t == 0) clusters[step] = (int)win;
        // uniform scalar fetch of winner coords (no 2nd barrier needed)
        const unsigned int winu = (unsigned int)__builtin_amdgcn_readfirstlane((int)win);
        lx = pos[winu * 3 + 0];
        ly = pos[winu * 3 + 1];
        lz = pos[winu * 3 + 2];
    }
#undef PAIR_STAGE
}

// ---------------------------------------------------------------------------
// kNN: one block per cluster, 256 threads. d = (qq+pp) - 2*dot (dot FMA-
// ascending like BLAS), LDS distance array per 8192-chunk, 16 argmin rounds
// per chunk (tie -> lower index == stable top_k), exact merge of 2x16.
// Only the neighbor SET matters downstream.
// ---------------------------------------------------------------------------
__global__ __launch_bounds__(256) void knn_kernel(const float* __restrict__ pos,
                                                  const float* __restrict__ pp,
                                                  const int* __restrict__ clusters,
                                                  int* __restrict__ nbr) {
#pragma clang fp contract(off)
    __shared__ float s_d[8192];
    __shared__ float s_rv[4];
    __shared__ int   s_ri[4];
    __shared__ float s_tv[32];
    __shared__ int   s_ti[32];
    const int m = blockIdx.x, t = threadIdx.x;
    const int lane = t & 63, w = t >> 6;

    const int qi = clusters[m];
    const float qx = pos[qi * 3 + 0], qy = pos[qi * 3 + 1], qz = pos[qi * 3 + 2];
    const float qq = ((qx * qx) + (qy * qy)) + (qz * qz);

    for (int chunk = 0; chunk < 2; ++chunk) {
        const int base = chunk << 13;
        __syncthreads();  // protect s_d overwrite vs previous chunk's reads
        for (int i = t; i < 8192; i += 256) {
            const int p = base + i;
            float dot = fmaf(qx, pos[p * 3 + 0], 0.0f);
            dot = fmaf(qy, pos[p * 3 + 1], dot);
            dot = fmaf(qz, pos[p * 3 + 2], dot);
            s_d[i] = (qq + pp[p]) - 2.0f * dot;
        }
        __syncthreads();
        for (int r = 0; r < KNN_K; ++r) {
            float bv = __builtin_inff();
            int   bi = 0x7fffffff;
            for (int i = t; i < 8192; i += 256) {   // i ascending per thread
                float v = s_d[i];
                if (v < bv) { bv = v; bi = i; }     // strict < keeps first
            }
#pragma unroll
            for (int off = 32; off >= 1; off >>= 1) {
                float ov = __shfl_down(bv, off);
                int   oi = __shfl_down(bi, off);
                if (ov < bv || (ov == bv && oi < bi)) { bv = ov; bi = oi; }
            }
            if (lane == 0) { s_rv[w] = bv; s_ri[w] = bi; }
            __syncthreads();
            if (t == 0) {
                float fv = s_rv[0]; int fi = s_ri[0];
#pragma unroll
                for (int ww = 1; ww < 4; ++ww) {
                    if (s_rv[ww] < fv || (s_rv[ww] == fv && s_ri[ww] < fi)) {
                        fv = s_rv[ww]; fi = s_ri[ww];
                    }
                }
                s_tv[chunk * 16 + r] = fv;
                s_ti[chunk * 16 + r] = base + fi;
                s_d[fi] = __builtin_inff();
            }
            __syncthreads();
        }
    }
    if (t == 0) {   // exact merge of two sorted-by-(v,idx) lists
        int a = 0, b = 0;
        for (int r = 0; r < KNN_K; ++r) {
            bool takeA;
            if (b >= 16) takeA = true;
            else if (a >= 16) takeA = false;
            else {
                float va = s_tv[a], vb = s_tv[16 + b];
                takeA = (va < vb) || (va == vb && s_ti[a] < s_ti[16 + b]);
            }
            nbr[m * KNN_K + r] = takeA ? s_ti[a] : s_ti[16 + b];
            if (takeA) ++a; else ++b;
        }
    }
}

// ---------------------------------------------------------------------------
// MLP: grouped[r] = [pos[n]-pos[r>>4] (quirky full-pos indexing!), x[n]],
// h = grouped @ W^T.  PASS 1: accumulate column sum/sumsq.  PASS 2:
// recompute, y = scale*h+shift, out[m,c] = relu(max_k y) (relu∘max=max∘relu),
// plus sub_pos / sub_batch.  64 rows (= 4 whole clusters) x 128 cols / block.
// ---------------------------------------------------------------------------
template <int PASS>
__global__ __launch_bounds__(256) void mlp_kernel(const float* __restrict__ x,
                                                  const float* __restrict__ pos,
                                                  const int* __restrict__ nbr,
                                                  const float* __restrict__ W,
                                                  float* __restrict__ colsum,
                                                  float* __restrict__ colsumsq,
                                                  const float* __restrict__ ss,
                                                  const int* __restrict__ clusters,
                                                  const int* __restrict__ batch,
                                                  float* __restrict__ out) {
    __shared__ __align__(16) float At[FAN_IN][68];     // [i][r], pad 68
    __shared__ __align__(16) float Wl[FAN_IN * 132];   // [i][c], pad 132
    __shared__ float red0[128], red1[128];
    __shared__ float hm[8][132];                       // pass2 half-cluster maxima
    const int tid = threadIdx.x;
    const int R0 = blockIdx.x * 64;

    // stage W transposed
    for (int idx = tid; idx < FAN_IN * 128; idx += 256) {
        int i = idx >> 7, c = idx & 127;
        Wl[i * 132 + c] = W[c * FAN_IN + i];
    }
    // stage A transposed (gather)
    {
        const int wv = tid >> 6, lane = tid & 63;
        for (int r = wv; r < 64; r += 4) {
            const int R = R0 + r;
            const int n = nbr[R];
            At[3 + lane][r] = x[n * C_IN + lane];
            if (lane < 3) {
                const int q = R >> 4;  // faithful to source: cluster ORDINAL indexes pos
                At[lane][r] = pos[n * 3 + lane] - pos[q * 3 + lane];
            }
        }
    }
    if (PASS == 1 && tid < 128) { red0[tid] = 0.0f; red1[tid] = 0.0f; }
    __syncthreads();

    const int g = tid & 31, rg = tid >> 5;
    const int c0 = g * 4, r0 = rg * 8;
    float acc[8][4];
#pragma unroll
    for (int a = 0; a < 8; ++a)
#pragma unroll
        for (int b = 0; b < 4; ++b) acc[a][b] = 0.0f;

    for (int i = 0; i < FAN_IN; ++i) {
        const float4 w4 = *(const float4*)&Wl[i * 132 + c0];
        const float4 a0 = *(const float4*)&At[i][r0];
        const float4 a1 = *(const float4*)&At[i][r0 + 4];
        const float av[8] = {a0.x, a0.y, a0.z, a0.w, a1.x, a1.y, a1.z, a1.w};
        const float wv4[4] = {w4.x, w4.y, w4.z, w4.w};
#pragma unroll
        for (int a = 0; a < 8; ++a)
#pragma unroll
            for (int b = 0; b < 4; ++b) acc[a][b] = fmaf(av[a], wv4[b], acc[a][b]);
    }

    if (PASS == 1) {
#pragma unroll
        for (int b = 0; b < 4; ++b) {
            float s = 0.0f, sq = 0.0f;
#pragma unroll
            for (int a = 0; a < 8; ++a) {
                s += acc[a][b];
                sq = fmaf(acc[a][b], acc[a][b], sq);
            }
            atomicAdd(&red0[c0 + b], s);
            atomicAdd(&red1[c0 + b], sq);
        }
        __syncthreads();
        if (tid < 128) {
            atomicAdd(&colsum[tid], red0[tid]);
            atomicAdd(&colsumsq[tid], red1[tid]);
        }
    } else {
        // rows r0..r0+7 lie in ONE cluster (half of it): reduce then combine
#pragma unroll
        for (int b = 0; b < 4; ++b) {
            const float sc = ss[c0 + b], sh = ss[128 + c0 + b];
            float mx = -__builtin_inff();
#pragma unroll
            for (int a = 0; a < 8; ++a) mx = fmaxf(mx, fmaf(sc, acc[a][b], sh));
            hm[rg][c0 + b] = mx;
        }
        __syncthreads();
        for (int o = tid; o < 512; o += 256) {
            const int cl = o >> 7, c = o & 127;
            const float v = fmaxf(hm[2 * cl][c], hm[2 * cl + 1][c]);
            const int M = blockIdx.x * 4 + cl;
            out[M * 128 + c] = fmaxf(v, 0.0f);
        }
        if (tid < 12) {
            const int cl = tid / 3, l = tid % 3;
            const int M = blockIdx.x * 4 + cl;
            out[524288 + M * 3 + l] = pos[clusters[M] * 3 + l];
        } else if (tid < 16) {
            const int M = blockIdx.x * 4 + (tid - 12);
            out[536576 + M] = (float)batch[clusters[M]];
        }
    }
}

// ---------------------------------------------------------------------------
// stats: scale/shift from column sums (biased var, like torch BN training)
// ---------------------------------------------------------------------------
__global__ void stats_kernel(const float* __restrict__ colsum,
                             const float* __restrict__ colsumsq,
                             const float* __restrict__ gamma,
                             const float* __restrict__ beta,
                             float* __restrict__ ss) {
    const int c = threadIdx.x;
    const float inv_n = 1.0f / (float)N_ROWS;
    const float mean = colsum[c] * inv_n;
    float var = colsumsq[c] * inv_n - mean * mean;
    var = fmaxf(var, 0.0f);
    const float inv = rsqrtf(var + 1e-5f);
    const float sc = gamma[c] * inv;
    ss[c] = sc;
    ss[128 + c] = beta[c] - mean * sc;
}

// ---------------------------------------------------------------------------
extern "C" void kernel_launch(void* const* d_in, const int* in_sizes, int n_in,
                              void* d_out, int out_size, void* d_ws, size_t ws_size,
                              hipStream_t stream) {
    const float* x     = (const float*)d_in[0];
    const float* pos   = (const float*)d_in[1];
    const int*   batch = (const int*)d_in[2];
    const float* W     = (const float*)d_in[3];
    const float* gamma = (const float*)d_in[4];
    const float* beta  = (const float*)d_in[5];
    float* out = (float*)d_out;
    float* wsf = (float*)d_ws;

    int*   clusters = (int*)d_ws;            // [4096]
    int*   nbr      = clusters + 4096;       // [65536]
    float* pp       = wsf + 69632;           // [16384]
    float* colsum   = wsf + 86016;           // [128]
    float* colsumsq = wsf + 86144;           // [128]
    float* ss       = wsf + 86272;           // [256]

    init_kernel<<<dim3(64), dim3(256), 0, stream>>>(pos, pp, colsum);
    fps_kernel<<<dim3(1), dim3(1024), 0, stream>>>(pos, clusters);
    knn_kernel<<<dim3(N_CLUSTERS), dim3(256), 0, stream>>>(pos, pp, clusters, nbr);
    mlp_kernel<1><<<dim3(1024), dim3(256), 0, stream>>>(x, pos, nbr, W, colsum, colsumsq,
                                                        ss, clusters, batch, out);
    stats_kernel<<<dim3(1), dim3(128), 0, stream>>>(colsum, colsumsq, gamma, beta, ss);
    mlp_kernel<2><<<dim3(1024), dim3(256), 0, stream>>>(x, pos, nbr, W, colsum, colsumsq,
                                                        ss, clusters, batch, out);
}

// Round 3
// 7367.001 us; speedup vs baseline: 1.3765x; 1.0418x over previous
//
#include <hip/hip_runtime.h>
#include <math.h>

#define N_PTS 16384
#define N_CLUSTERS 4096
#define KNN_K 16
#define C_IN 64
#define C_OUT 128
#define FAN_IN 67
#define N_ROWS (N_CLUSTERS * KNN_K)   // 65536

typedef float vf2 __attribute__((ext_vector_type(2)));

// ---------------------------------------------------------------------------
// init: pp[i] = |pos_i|^2 (reference op order, no FMA), zero colsum/colsumsq
// ---------------------------------------------------------------------------
__global__ void init_kernel(const float* __restrict__ pos, float* __restrict__ pp,
                            float* __restrict__ cz) {
#pragma clang fp contract(off)
    int i = blockIdx.x * 256 + threadIdx.x;
    if (i < N_PTS) {
        float a = pos[i * 3 + 0], b = pos[i * 3 + 1], c = pos[i * 3 + 2];
        pp[i] = ((a * a) + (b * b)) + (c * c);
    }
    if (blockIdx.x == 0 && threadIdx.x < 256) cz[threadIdx.x] = 0.0f;
}

// ---------------------------------------------------------------------------
// FPS v3: single block, 1024 threads, 16 points/thread in registers as
// float2 pairs (v_pk_add_f32 / v_pk_mul_f32 full-rate packed fp32).
// amdgpu_waves_per_eu(4,4) -> allocator may use 128 VGPRs (16 waves/CU is
// fixed anyway: single block) -> no AGPR/scratch shuffling of the arrays.
// Bit-exact vs reference: d = ((dx*dx)+(dy*dy))+(dz*dz) per element, no FMA,
// argmax with first-index tie-break (pair order is idx-ascending).
//   pair a, comp {x,y} owns global idx t + (2a+comp)<<10
// ---------------------------------------------------------------------------
__global__ __launch_bounds__(1024)
__attribute__((amdgpu_waves_per_eu(4, 4)))
void fps_kernel(const float* __restrict__ pos, int* __restrict__ clusters) {
#pragma clang fp contract(off)
    __shared__ unsigned long long s_key[4];
    const int t = threadIdx.x;

    vf2 ax[8], ay[8], az[8], mdv[8];
#pragma unroll
    for (int a = 0; a < 8; ++a) {
        const int g0 = t + ((2 * a) << 10);
        const int g1 = g0 + 1024;
        ax[a] = (vf2){pos[g0 * 3 + 0], pos[g1 * 3 + 0]};
        ay[a] = (vf2){pos[g0 * 3 + 1], pos[g1 * 3 + 1]};
        az[a] = (vf2){pos[g0 * 3 + 2], pos[g1 * 3 + 2]};
        mdv[a] = (vf2){__builtin_inff(), __builtin_inff()};
    }
    if (t == 0) clusters[0] = 0;
    if (t < 4) s_key[t] = 0ULL;
    float lx = pos[0], ly = pos[1], lz = pos[2];
    __syncthreads();

// DPP pair-max stage: (hi,lo) = max over incoming lanes, key order = u64.
// old=0 for masked/invalid lanes: key 0 never wins (lo = ~idx != 0).
#define PAIR_STAGE(CTRL, RM)                                                          \
    do {                                                                              \
        unsigned int ohi = (unsigned int)__builtin_amdgcn_update_dpp(                 \
            0, (int)hi, (CTRL), (RM), 0xF, false);                                    \
        unsigned int olo = (unsigned int)__builtin_amdgcn_update_dpp(                 \
            0, (int)lo, (CTRL), (RM), 0xF, false);                                    \
        unsigned long long cur = ((unsigned long long)hi << 32) | lo;                 \
        unsigned long long oth = ((unsigned long long)ohi << 32) | olo;               \
        if (oth > cur) { hi = ohi; lo = olo; }                                        \
    } while (0)

    for (int step = 1; step < N_CLUSTERS; ++step) {
        const vf2 lxv = (vf2){lx, lx}, lyv = (vf2){ly, ly}, lzv = (vf2){lz, lz};
        // --- packed min-distance update (pk_add/pk_mul; per-element order
        //     identical to reference) ---
        vf2 bm = (vf2){0.0f, 0.0f};
#pragma unroll
        for (int a = 0; a < 8; ++a) {
            vf2 dx = ax[a] - lxv;
            vf2 dy = ay[a] - lyv;
            vf2 dz = az[a] - lzv;
            vf2 d = ((dx * dx) + (dy * dy)) + (dz * dz);
            vf2 m = __builtin_elementwise_min(mdv[a], d);
            mdv[a] = m;
            bm = __builtin_elementwise_max(bm, m);
        }
        const float bv = fmaxf(bm.x, bm.y);

        // --- recover first (smallest) local index achieving bv ---
        int bj = 0;
#pragma unroll
        for (int a = 7; a >= 0; --a) {
            bj = (mdv[a].y == bv) ? 2 * a + 1 : bj;
            bj = (mdv[a].x == bv) ? 2 * a : bj;
        }
        const unsigned int bi = (unsigned int)(t + (bj << 10));

        // --- wave64 DPP pair-max; result lands in lane 63 ---
        unsigned int hi = __float_as_uint(bv);
        unsigned int lo = ~bi;  // max(~idx) == min(idx) tie-break
        PAIR_STAGE(0x111, 0xF);  // row_shr:1
        PAIR_STAGE(0x112, 0xF);  // row_shr:2
        PAIR_STAGE(0x114, 0xF);  // row_shr:4
        PAIR_STAGE(0x118, 0xF);  // row_shr:8
        PAIR_STAGE(0x142, 0xA);  // row_bcast:15 -> rows 1,3
        PAIR_STAGE(0x143, 0xC);  // row_bcast:31 -> rows 2,3

        if ((t & 63) == 63)
            atomicMax(&s_key[step & 3], (((unsigned long long)hi << 32) | lo));
        if (t == 0) s_key[(step + 2) & 3] = 0ULL;  // reset slot for step+2
        __syncthreads();

        const unsigned long long k = s_key[step & 3];
        const unsigned int win = ~((unsigned int)k);
        if (t == 0) clusters[step] = (int)win;
        // uniform scalar fetch of winner coords (no 2nd barrier needed)
        const unsigned int winu = (unsigned int)__builtin_amdgcn_readfirstlane((int)win);
        lx = pos[winu * 3 + 0];
        ly = pos[winu * 3 + 1];
        lz = pos[winu * 3 + 2];
    }
#undef PAIR_STAGE
}

// ---------------------------------------------------------------------------
// kNN: one block per cluster, 256 threads. d = (qq+pp) - 2*dot (dot FMA-
// ascending like BLAS), LDS distance array per 8192-chunk, 16 argmin rounds
// per chunk (tie -> lower index == stable top_k), exact merge of 2x16.
// Only the neighbor SET matters downstream.
// ---------------------------------------------------------------------------
__global__ __launch_bounds__(256) void knn_kernel(const float* __restrict__ pos,
                                                  const float* __restrict__ pp,
                                                  const int* __restrict__ clusters,
                                                  int* __restrict__ nbr) {
#pragma clang fp contract(off)
    __shared__ float s_d[8192];
    __shared__ float s_rv[4];
    __shared__ int   s_ri[4];
    __shared__ float s_tv[32];
    __shared__ int   s_ti[32];
    const int m = blockIdx.x, t = threadIdx.x;
    const int lane = t & 63, w = t >> 6;

    const int qi = clusters[m];
    const float qx = pos[qi * 3 + 0], qy = pos[qi * 3 + 1], qz = pos[qi * 3 + 2];
    const float qq = ((qx * qx) + (qy * qy)) + (qz * qz);

    for (int chunk = 0; chunk < 2; ++chunk) {
        const int base = chunk << 13;
        __syncthreads();  // protect s_d overwrite vs previous chunk's reads
        for (int i = t; i < 8192; i += 256) {
            const int p = base + i;
            float dot = fmaf(qx, pos[p * 3 + 0], 0.0f);
            dot = fmaf(qy, pos[p * 3 + 1], dot);
            dot = fmaf(qz, pos[p * 3 + 2], dot);
            s_d[i] = (qq + pp[p]) - 2.0f * dot;
        }
        __syncthreads();
        for (int r = 0; r < KNN_K; ++r) {
            float bv = __builtin_inff();
            int   bi = 0x7fffffff;
            for (int i = t; i < 8192; i += 256) {   // i ascending per thread
                float v = s_d[i];
                if (v < bv) { bv = v; bi = i; }     // strict < keeps first
            }
#pragma unroll
            for (int off = 32; off >= 1; off >>= 1) {
                float ov = __shfl_down(bv, off);
                int   oi = __shfl_down(bi, off);
                if (ov < bv || (ov == bv && oi < bi)) { bv = ov; bi = oi; }
            }
            if (lane == 0) { s_rv[w] = bv; s_ri[w] = bi; }
            __syncthreads();
            if (t == 0) {
                float fv = s_rv[0]; int fi = s_ri[0];
#pragma unroll
                for (int ww = 1; ww < 4; ++ww) {
                    if (s_rv[ww] < fv || (s_rv[ww] == fv && s_ri[ww] < fi)) {
                        fv = s_rv[ww]; fi = s_ri[ww];
                    }
                }
                s_tv[chunk * 16 + r] = fv;
                s_ti[chunk * 16 + r] = base + fi;
                s_d[fi] = __builtin_inff();
            }
            __syncthreads();
        }
    }
    if (t == 0) {   // exact merge of two sorted-by-(v,idx) lists
        int a = 0, b = 0;
        for (int r = 0; r < KNN_K; ++r) {
            bool takeA;
            if (b >= 16) takeA = true;
            else if (a >= 16) takeA = false;
            else {
                float va = s_tv[a], vb = s_tv[16 + b];
                takeA = (va < vb) || (va == vb && s_ti[a] < s_ti[16 + b]);
            }
            nbr[m * KNN_K + r] = takeA ? s_ti[a] : s_ti[16 + b];
            if (takeA) ++a; else ++b;
        }
    }
}

// ---------------------------------------------------------------------------
// MLP: grouped[r] = [pos[n]-pos[r>>4] (quirky full-pos indexing!), x[n]],
// h = grouped @ W^T.  PASS 1: accumulate column sum/sumsq.  PASS 2:
// recompute, y = scale*h+shift, out[m,c] = relu(max_k y) (relu∘max=max∘relu),
// plus sub_pos / sub_batch.  64 rows (= 4 whole clusters) x 128 cols / block.
// ---------------------------------------------------------------------------
template <int PASS>
__global__ __launch_bounds__(256) void mlp_kernel(const float* __restrict__ x,
                                                  const float* __restrict__ pos,
                                                  const int* __restrict__ nbr,
                                                  const float* __restrict__ W,
                                                  float* __restrict__ colsum,
                                                  float* __restrict__ colsumsq,
                                                  const float* __restrict__ ss,
                                                  const int* __restrict__ clusters,
                                                  const int* __restrict__ batch,
                                                  float* __restrict__ out) {
    __shared__ __align__(16) float At[FAN_IN][68];     // [i][r], pad 68
    __shared__ __align__(16) float Wl[FAN_IN * 132];   // [i][c], pad 132
    __shared__ float red0[128], red1[128];
    __shared__ float hm[8][132];                       // pass2 half-cluster maxima
    const int tid = threadIdx.x;
    const int R0 = blockIdx.x * 64;

    // stage W transposed
    for (int idx = tid; idx < FAN_IN * 128; idx += 256) {
        int i = idx >> 7, c = idx & 127;
        Wl[i * 132 + c] = W[c * FAN_IN + i];
    }
    // stage A transposed (gather)
    {
        const int wv = tid >> 6, lane = tid & 63;
        for (int r = wv; r < 64; r += 4) {
            const int R = R0 + r;
            const int n = nbr[R];
            At[3 + lane][r] = x[n * C_IN + lane];
            if (lane < 3) {
                const int q = R >> 4;  // faithful to source: cluster ORDINAL indexes pos
                At[lane][r] = pos[n * 3 + lane] - pos[q * 3 + lane];
            }
        }
    }
    if (PASS == 1 && tid < 128) { red0[tid] = 0.0f; red1[tid] = 0.0f; }
    __syncthreads();

    const int g = tid & 31, rg = tid >> 5;
    const int c0 = g * 4, r0 = rg * 8;
    float acc[8][4];
#pragma unroll
    for (int a = 0; a < 8; ++a)
#pragma unroll
        for (int b = 0; b < 4; ++b) acc[a][b] = 0.0f;

    for (int i = 0; i < FAN_IN; ++i) {
        const float4 w4 = *(const float4*)&Wl[i * 132 + c0];
        const float4 a0 = *(const float4*)&At[i][r0];
        const float4 a1 = *(const float4*)&At[i][r0 + 4];
        const float av[8] = {a0.x, a0.y, a0.z, a0.w, a1.x, a1.y, a1.z, a1.w};
        const float wv4[4] = {w4.x, w4.y, w4.z, w4.w};
#pragma unroll
        for (int a = 0; a < 8; ++a)
#pragma unroll
            for (int b = 0; b < 4; ++b) acc[a][b] = fmaf(av[a], wv4[b], acc[a][b]);
    }

    if (PASS == 1) {
#pragma unroll
        for (int b = 0; b < 4; ++b) {
            float s = 0.0f, sq = 0.0f;
#pragma unroll
            for (int a = 0; a < 8; ++a) {
                s += acc[a][b];
                sq = fmaf(acc[a][b], acc[a][b], sq);
            }
            atomicAdd(&red0[c0 + b], s);
            atomicAdd(&red1[c0 + b], sq);
        }
        __syncthreads();
        if (tid < 128) {
            atomicAdd(&colsum[tid], red0[tid]);
            atomicAdd(&colsumsq[tid], red1[tid]);
        }
    } else {
        // rows r0..r0+7 lie in ONE cluster (half of it): reduce then combine
#pragma unroll
        for (int b = 0; b < 4; ++b) {
            const float sc = ss[c0 + b], sh = ss[128 + c0 + b];
            float mx = -__builtin_inff();
#pragma unroll
            for (int a = 0; a < 8; ++a) mx = fmaxf(mx, fmaf(sc, acc[a][b], sh));
            hm[rg][c0 + b] = mx;
        }
        __syncthreads();
        for (int o = tid; o < 512; o += 256) {
            const int cl = o >> 7, c = o & 127;
            const float v = fmaxf(hm[2 * cl][c], hm[2 * cl + 1][c]);
            const int M = blockIdx.x * 4 + cl;
            out[M * 128 + c] = fmaxf(v, 0.0f);
        }
        if (tid < 12) {
            const int cl = tid / 3, l = tid % 3;
            const int M = blockIdx.x * 4 + cl;
            out[524288 + M * 3 + l] = pos[clusters[M] * 3 + l];
        } else if (tid < 16) {
            const int M = blockIdx.x * 4 + (tid - 12);
            out[536576 + M] = (float)batch[clusters[M]];
        }
    }
}

// ---------------------------------------------------------------------------
// stats: scale/shift from column sums (biased var, like torch BN training)
// ---------------------------------------------------------------------------
__global__ void stats_kernel(const float* __restrict__ colsum,
                             const float* __restrict__ colsumsq,
                             const float* __restrict__ gamma,
                             const float* __restrict__ beta,
                             float* __restrict__ ss) {
    const int c = threadIdx.x;
    const float inv_n = 1.0f / (float)N_ROWS;
    const float mean = colsum[c] * inv_n;
    float var = colsumsq[c] * inv_n - mean * mean;
    var = fmaxf(var, 0.0f);
    const float inv = rsqrtf(var + 1e-5f);
    const float sc = gamma[c] * inv;
    ss[c] = sc;
    ss[128 + c] = beta[c] - mean * sc;
}

// ---------------------------------------------------------------------------
extern "C" void kernel_launch(void* const* d_in, const int* in_sizes, int n_in,
                              void* d_out, int out_size, void* d_ws, size_t ws_size,
                              hipStream_t stream) {
    const float* x     = (const float*)d_in[0];
    const float* pos   = (const float*)d_in[1];
    const int*   batch = (const int*)d_in[2];
    const float* W     = (const float*)d_in[3];
    const float* gamma = (const float*)d_in[4];
    const float* beta  = (const float*)d_in[5];
    float* out = (float*)d_out;
    float* wsf = (float*)d_ws;

    int*   clusters = (int*)d_ws;            // [4096]
    int*   nbr      = clusters + 4096;       // [65536]
    float* pp       = wsf + 69632;           // [16384]
    float* colsum   = wsf + 86016;           // [128]
    float* colsumsq = wsf + 86144;           // [128]
    float* ss       = wsf + 86272;           // [256]

    init_kernel<<<dim3(64), dim3(256), 0, stream>>>(pos, pp, colsum);
    fps_kernel<<<dim3(1), dim3(1024), 0, stream>>>(pos, clusters);
    knn_kernel<<<dim3(N_CLUSTERS), dim3(256), 0, stream>>>(pos, pp, clusters, nbr);
    mlp_kernel<1><<<dim3(1024), dim3(256), 0, stream>>>(x, pos, nbr, W, colsum, colsumsq,
                                                        ss, clusters, batch, out);
    stats_kernel<<<dim3(1), dim3(128), 0, stream>>>(colsum, colsumsq, gamma, beta, ss);
    mlp_kernel<2><<<dim3(1024), dim3(256), 0, stream>>>(x, pos, nbr, W, colsum, colsumsq,
                                                        ss, clusters, batch, out);
}